// Round 4
// baseline (645.249 us; speedup 1.0000x reference)
//
#include <hip/hip_runtime.h>

#define BATCH 512
#define FEATURES 256
#define ENC 2048
#define HIDDEN 8192
#define CLASSES 1000
#define THRESH 16
#define PAIR_CAP 65536
#define MAXACT 256
#define NBLK 2048
#define OUTBLK 64

typedef unsigned long long u64;
typedef unsigned int u32;

// -------- workspace layout (bytes) --------
// ctr   : [0]=npairs [1]=prep_done [2]=z1_done [3]=prep_ticket  (memset to 0)
// a0t   : ENC cols x 64 B (512-bit batch mask per encoded column) = 131072
// pairs : PAIR_CAP u32, entry = (b << 13) | n
#define OFF_CTR   0
#define OFF_A0T   256
#define OFF_PAIRS (256 + 131072)

__global__ __launch_bounds__(256) void fused_kernel(
    const float* __restrict__ x, const float* __restrict__ W1,
    const float* __restrict__ W2, const float* __restrict__ Wout,
    u32* ctr, u32* a0t_w, u32* pairs, float* outp, float* pred)
{
    const unsigned char* a0t = (const unsigned char*)a0t_w;
    int tid = threadIdx.x;
    int wid = tid >> 6, lane = tid & 63;
    __shared__ int colsAll[4][40];
    __shared__ int ticket_s;
    __shared__ int act1[MAXACT], act2[MAXACT];
    __shared__ int n1s, n2s;
    __shared__ float rv[256];
    __shared__ int ri[256];

    // ---- prep via work-stealing: first 16 RUNNING blocks build a0t ----
    if (tid == 0) ticket_s = (int)atomicAdd(&ctr[3], 1u);
    __syncthreads();
    if (ticket_s < 16) {                 // block-uniform branch
        int w = ticket_s, f = tid;       // 32-batch word w, feature f
        u32 m[8] = {0,0,0,0,0,0,0,0};
        for (int i = 0; i < 32; ++i) {
            float v = x[(w * 32 + i) * FEATURES + f];
            v = fminf(fmaxf(v, 0.0f), 1.0f);
            int lvl = (int)rintf(v * 255.0f);   // round-half-even == np.round
            int g = lvl ^ (lvl >> 1);
            u32 bit = 1u << i;
#pragma unroll
            for (int k = 0; k < 8; ++k) if ((g >> k) & 1) m[k] |= bit;
        }
#pragma unroll
        for (int k = 0; k < 8; ++k) a0t_w[(f * 8 + k) * 16 + w] = m[k];
        __threadfence();
        __syncthreads();
        if (tid == 0)
            __hip_atomic_fetch_add(&ctr[1], 1u, __ATOMIC_RELEASE, __HIP_MEMORY_SCOPE_AGENT);
    }

    // ---- z1 phase A: stream W1 row (float4), compact (col,sign) to LDS ----
    // (no a0t dependency — the 64 MB stream hides prep latency)
    int n = blockIdx.x * 4 + wid;
    const float4* rowv = reinterpret_cast<const float4*>(W1 + (size_t)n * ENC);
    int* cols = colsAll[wid];
    int cnt = 0;
    u64 lmask = (lane == 63) ? 0x7fffffffffffffffULL : ((1ULL << lane) - 1ULL);
    for (int it = 0; it < 8; ++it) {
        float4 v = rowv[it * 64 + lane];
#pragma unroll
        for (int c = 0; c < 4; ++c) {
            float vc = (c == 0) ? v.x : (c == 1) ? v.y : (c == 2) ? v.z : v.w;
            u64 mm = __ballot(vc != 0.0f);
            if (vc != 0.0f) {
                int pos = cnt + __popcll(mm & lmask);
                cols[pos] = ((it * 256 + lane * 4 + c) << 1) | (vc < 0.0f ? 1 : 0);
            }
            cnt += __popcll(mm);
        }
    }

    // ---- wait for a0t ready ----
    if (tid == 0) {
        while (__hip_atomic_load(&ctr[1], __ATOMIC_ACQUIRE, __HIP_MEMORY_SCOPE_AGENT) < 16u)
            __builtin_amdgcn_s_sleep(2);
    }
    __syncthreads();
    __threadfence();

    // ---- z1 phase B: bit-sliced carry-save accumulate over entries ----
    u32 p0=0,p1=0,p2=0,p3=0,p4=0,p5=0;
    u32 q0=0,q1=0,q2=0,q3=0,q4=0,q5=0;
#pragma unroll 4
    for (int i = 0; i < cnt; ++i) {
        int e = __builtin_amdgcn_readfirstlane(cols[i]);
        u32 m = a0t[(size_t)(e >> 1) * 64 + lane];
        if (e & 1) {   // negative (wave-uniform branch)
            u32 t;
            t = q0 & m; q0 ^= m; m = t;
            t = q1 & m; q1 ^= m; m = t;
            t = q2 & m; q2 ^= m; m = t;
            t = q3 & m; q3 ^= m; m = t;
            t = q4 & m; q4 ^= m; m = t;
            q5 ^= m;
        } else {
            u32 t;
            t = p0 & m; p0 ^= m; m = t;
            t = p1 & m; p1 ^= m; m = t;
            t = p2 & m; p2 ^= m; m = t;
            t = p3 & m; p3 ^= m; m = t;
            p5 ^= (p4 & m); p4 ^= m;  // fold last carry into p5
        }
    }

    u32 cand = p4 | p5;     // bytes where P >= 16 possible (z>=16 requires P>=16)
    while (cand) {
        int k = __ffs(cand) - 1;
        cand &= cand - 1;
        int P = ((p0 >> k) & 1) | (((p1 >> k) & 1) << 1) | (((p2 >> k) & 1) << 2) |
                (((p3 >> k) & 1) << 3) | (((p4 >> k) & 1) << 4) | (((p5 >> k) & 1) << 5);
        int N = ((q0 >> k) & 1) | (((q1 >> k) & 1) << 1) | (((q2 >> k) & 1) << 2) |
                (((q3 >> k) & 1) << 3) | (((q4 >> k) & 1) << 4) | (((q5 >> k) & 1) << 5);
        if (P - N >= THRESH) {
            int b = lane * 8 + k;
            u32 pos = atomicAdd(&ctr[0], 1u);
            if (pos < PAIR_CAP)
                __hip_atomic_store(&pairs[pos], ((u32)b << 13) | (u32)n,
                                   __ATOMIC_RELAXED, __HIP_MEMORY_SCOPE_AGENT);
        }
    }

    // ---- signal z1 done ----
    __syncthreads();
    if (tid == 0) {
        __threadfence();
        __hip_atomic_fetch_add(&ctr[2], 1u, __ATOMIC_RELEASE, __HIP_MEMORY_SCOPE_AGENT);
    }
    if (blockIdx.x >= OUTBLK) return;

    // ---- out phase: 64 blocks x 8 batches, wait for all z1 ----
    if (tid == 0) {
        while (__hip_atomic_load(&ctr[2], __ATOMIC_ACQUIRE, __HIP_MEMORY_SCOPE_AGENT) < (u32)NBLK)
            __builtin_amdgcn_s_sleep(2);
    }
    __syncthreads();
    __threadfence();

    int tot = (int)__hip_atomic_load(&ctr[0], __ATOMIC_RELAXED, __HIP_MEMORY_SCOPE_AGENT);
    if (tot > PAIR_CAP) tot = PAIR_CAP;

    for (int j = 0; j < 8; ++j) {
        int b = blockIdx.x * 8 + j;
        __syncthreads();                 // protect act reuse across batches
        if (tid == 0) { n1s = 0; n2s = 0; }
        __syncthreads();

        for (int i = tid; i < tot; i += 256) {
            u32 p = __hip_atomic_load(&pairs[i], __ATOMIC_RELAXED, __HIP_MEMORY_SCOPE_AGENT);
            if ((int)(p >> 13) == b) {
                int pos = atomicAdd(&n1s, 1);
                if (pos < MAXACT) act1[pos] = (int)(p & 8191u);
            }
        }
        __syncthreads();
        if (tid == 0) {
            int c = n1s; if (c > MAXACT) { c = MAXACT; n1s = c; }
            for (int i = 1; i < c; ++i) {            // deterministic ascending order
                int v = act1[i], k = i;
                while (k > 0 && act1[k - 1] > v) { act1[k] = act1[k - 1]; --k; }
                act1[k] = v;
            }
        }
        __syncthreads();
        int na1 = n1s;

        if (na1 >= THRESH) {   // exactness path; W2 entries <= +1 make z2<16 otherwise
            for (int nn = tid; nn < HIDDEN; nn += 256) {
                int z = 0;
                for (int i = 0; i < na1; ++i) z += (int)W2[(size_t)nn * HIDDEN + act1[i]];
                if (z >= THRESH) {
                    int pos = atomicAdd(&n2s, 1);
                    if (pos < MAXACT) act2[pos] = nn;
                }
            }
            __syncthreads();
            if (tid == 0) {
                int c = n2s; if (c > MAXACT) { c = MAXACT; n2s = c; }
                for (int i = 1; i < c; ++i) {
                    int v = act2[i], k = i;
                    while (k > 0 && act2[k - 1] > v) { act2[k] = act2[k - 1]; --k; }
                    act2[k] = v;
                }
            }
            __syncthreads();
        }
        int na2 = n2s;

        float s0 = 0.f, s1 = 0.f, s2 = 0.f, s3 = 0.f;
        for (int i = 0; i < na1; ++i) {
            const float* wr = Wout + (size_t)act1[i] * CLASSES;   // layer 0
            s0 += wr[tid];
            s1 += wr[tid + 256];
            s2 += wr[tid + 512];
            if (tid + 768 < CLASSES) s3 += wr[tid + 768];
        }
        for (int i = 0; i < na2; ++i) {
            const float* wr = Wout + (size_t)HIDDEN * CLASSES + (size_t)act2[i] * CLASSES;
            s0 += wr[tid];
            s1 += wr[tid + 256];
            s2 += wr[tid + 512];
            if (tid + 768 < CLASSES) s3 += wr[tid + 768];
        }

        float* orow = outp + (size_t)b * CLASSES;
        orow[tid]       = s0;
        orow[tid + 256] = s1;
        orow[tid + 512] = s2;
        if (tid + 768 < CLASSES) orow[tid + 768] = s3;

        // fused argmax (max value, min index on ties == numpy)
        float best = s0; int bi = tid;
        if (s1 > best) { best = s1; bi = tid + 256; }
        if (s2 > best) { best = s2; bi = tid + 512; }
        if (tid + 768 < CLASSES && s3 > best) { best = s3; bi = tid + 768; }
        rv[tid] = best; ri[tid] = bi;
        __syncthreads();
        for (int off = 128; off; off >>= 1) {
            if (tid < off) {
                float ov = rv[tid + off]; int oi = ri[tid + off];
                if (ov > rv[tid] || (ov == rv[tid] && oi < ri[tid])) { rv[tid] = ov; ri[tid] = oi; }
            }
            __syncthreads();
        }
        if (tid == 0) pred[b] = (float)ri[0];
    }
}

extern "C" void kernel_launch(void* const* d_in, const int* in_sizes, int n_in,
                              void* d_out, int out_size, void* d_ws, size_t ws_size,
                              hipStream_t stream) {
    (void)in_sizes; (void)n_in; (void)out_size; (void)ws_size;
    const float* x    = (const float*)d_in[0];
    const float* W1   = (const float*)d_in[1];
    const float* W2   = (const float*)d_in[2];
    const float* Wout = (const float*)d_in[3];

    float* pred = (float*)d_out;          // 512 predictions (as float)
    float* outp = (float*)d_out + BATCH;  // 512 x 1000 logits

    char* ws = (char*)d_ws;
    u32* ctr   = (u32*)(ws + OFF_CTR);
    u32* a0t_w = (u32*)(ws + OFF_A0T);
    u32* pairs = (u32*)(ws + OFF_PAIRS);

    hipMemsetAsync(ctr, 0, 16, stream);
    fused_kernel<<<NBLK, 256, 0, stream>>>(x, W1, W2, Wout, ctr, a0t_w, pairs, outp, pred);
}

// Round 5
// 161.530 us; speedup vs baseline: 3.9946x; 3.9946x over previous
//
#include <hip/hip_runtime.h>

#define BATCH 512
#define FEATURES 256
#define ENC 2048
#define HIDDEN 8192
#define CLASSES 1000
#define THRESH 16
#define PAIR_CAP 65536
#define MAXACT 256
#define NBLK 2048
#define OUTBLK 64

typedef unsigned long long u64;
typedef unsigned int u32;

// -------- workspace layout (bytes) --------
// ctr   : [0]=npairs [1]=prep_done [2]=z1_done [3]=prep_ticket  (memset to 0)
// a0t   : ENC cols x 64 B (512-bit batch mask per encoded column) = 131072
// pairs : PAIR_CAP u32, entry = (b << 13) | n
#define OFF_CTR   0
#define OFF_A0T   256
#define OFF_PAIRS (256 + 131072)

// Sync discipline (R4 post-mortem): agent-scope ACQUIRE loads in a spin loop
// emit a buffer_inv per iteration -> cache-invalidate storm that throttled the
// concurrent W1 stream to 55 GB/s. Poll RELAXED (goes to coherence point, no
// invalidate), s_sleep between polls, and issue ONE __threadfence() after the
// condition holds (single inv+wb = the acquire for plain-load data like a0t).

__global__ __launch_bounds__(256) void fused_kernel(
    const float* __restrict__ x, const float* __restrict__ W1,
    const float* __restrict__ W2, const float* __restrict__ Wout,
    u32* ctr, u32* a0t_w, u32* pairs, float* outp, float* pred)
{
    const unsigned char* a0t = (const unsigned char*)a0t_w;
    int tid = threadIdx.x;
    int wid = tid >> 6, lane = tid & 63;
    __shared__ int colsAll[4][40];
    __shared__ int ticket_s;
    __shared__ int act1[MAXACT], act2[MAXACT];
    __shared__ int n1s, n2s;
    __shared__ float rv[256];
    __shared__ int ri[256];

    // ---- prep via work-stealing: first 16 RUNNING blocks build a0t ----
    if (tid == 0) ticket_s = (int)atomicAdd(&ctr[3], 1u);
    __syncthreads();
    if (ticket_s < 16) {                 // block-uniform branch
        int w = ticket_s, f = tid;       // 32-batch word w, feature f
        u32 m[8] = {0,0,0,0,0,0,0,0};
        for (int i = 0; i < 32; ++i) {
            float v = x[(w * 32 + i) * FEATURES + f];
            v = fminf(fmaxf(v, 0.0f), 1.0f);
            int lvl = (int)rintf(v * 255.0f);   // round-half-even == np.round
            int g = lvl ^ (lvl >> 1);
            u32 bit = 1u << i;
#pragma unroll
            for (int k = 0; k < 8; ++k) if ((g >> k) & 1) m[k] |= bit;
        }
#pragma unroll
        for (int k = 0; k < 8; ++k) a0t_w[(f * 8 + k) * 16 + w] = m[k];
        __syncthreads();
        if (tid == 0)   // RELEASE publishes the plain a0t stores (16 total: cheap)
            __hip_atomic_fetch_add(&ctr[1], 1u, __ATOMIC_RELEASE, __HIP_MEMORY_SCOPE_AGENT);
    }

    // ---- z1 phase A: stream W1 row (float4), compact (col,sign) to LDS ----
    // (no a0t dependency — the 64 MB stream hides prep latency)
    int n = blockIdx.x * 4 + wid;
    const float4* rowv = reinterpret_cast<const float4*>(W1 + (size_t)n * ENC);
    int* cols = colsAll[wid];
    int cnt = 0;
    u64 lmask = (lane == 63) ? 0x7fffffffffffffffULL : ((1ULL << lane) - 1ULL);
    for (int it = 0; it < 8; ++it) {
        float4 v = rowv[it * 64 + lane];
#pragma unroll
        for (int c = 0; c < 4; ++c) {
            float vc = (c == 0) ? v.x : (c == 1) ? v.y : (c == 2) ? v.z : v.w;
            u64 mm = __ballot(vc != 0.0f);
            if (vc != 0.0f) {
                int pos = cnt + __popcll(mm & lmask);
                cols[pos] = ((it * 256 + lane * 4 + c) << 1) | (vc < 0.0f ? 1 : 0);
            }
            cnt += __popcll(mm);
        }
    }

    // ---- wait for a0t ready: RELAXED poll, fence once after ----
    if (tid == 0) {
        while (__hip_atomic_load(&ctr[1], __ATOMIC_RELAXED, __HIP_MEMORY_SCOPE_AGENT) < 16u)
            __builtin_amdgcn_s_sleep(32);
        __threadfence();   // single acquire: invalidate stale L1/L2 for a0t plain loads
    }
    __syncthreads();

    // ---- z1 phase B: bit-sliced carry-save accumulate over entries ----
    u32 p0=0,p1=0,p2=0,p3=0,p4=0,p5=0;
    u32 q0=0,q1=0,q2=0,q3=0,q4=0,q5=0;
#pragma unroll 4
    for (int i = 0; i < cnt; ++i) {
        int e = __builtin_amdgcn_readfirstlane(cols[i]);
        u32 m = a0t[(size_t)(e >> 1) * 64 + lane];
        if (e & 1) {   // negative (wave-uniform branch)
            u32 t;
            t = q0 & m; q0 ^= m; m = t;
            t = q1 & m; q1 ^= m; m = t;
            t = q2 & m; q2 ^= m; m = t;
            t = q3 & m; q3 ^= m; m = t;
            t = q4 & m; q4 ^= m; m = t;
            q5 ^= m;
        } else {
            u32 t;
            t = p0 & m; p0 ^= m; m = t;
            t = p1 & m; p1 ^= m; m = t;
            t = p2 & m; p2 ^= m; m = t;
            t = p3 & m; p3 ^= m; m = t;
            p5 ^= (p4 & m); p4 ^= m;
        }
    }

    u32 cand = p4 | p5;     // bytes where P >= 16 possible (z>=16 requires P>=16)
    while (cand) {
        int k = __ffs(cand) - 1;
        cand &= cand - 1;
        int P = ((p0 >> k) & 1) | (((p1 >> k) & 1) << 1) | (((p2 >> k) & 1) << 2) |
                (((p3 >> k) & 1) << 3) | (((p4 >> k) & 1) << 4) | (((p5 >> k) & 1) << 5);
        int N = ((q0 >> k) & 1) | (((q1 >> k) & 1) << 1) | (((q2 >> k) & 1) << 2) |
                (((q3 >> k) & 1) << 3) | (((q4 >> k) & 1) << 4) | (((q5 >> k) & 1) << 5);
        if (P - N >= THRESH) {
            int b = lane * 8 + k;
            u32 pos = atomicAdd(&ctr[0], 1u);
            if (pos < PAIR_CAP)
                __hip_atomic_store(&pairs[pos], ((u32)b << 13) | (u32)n,
                                   __ATOMIC_RELAXED, __HIP_MEMORY_SCOPE_AGENT);
        }
    }

    // ---- signal z1 done ----
    // __syncthreads() drains every wave's agent-scope pair stores (compiler
    // emits vmcnt(0) before s_barrier), and the stores already landed at the
    // coherence point -> RELAXED increment suffices (no 2048x release-wb storm).
    __syncthreads();
    if (tid == 0)
        __hip_atomic_fetch_add(&ctr[2], 1u, __ATOMIC_RELAXED, __HIP_MEMORY_SCOPE_AGENT);
    if (blockIdx.x >= OUTBLK) return;

    // ---- out phase: 64 blocks x 8 batches, wait for all z1 ----
    if (tid == 0) {
        while (__hip_atomic_load(&ctr[2], __ATOMIC_RELAXED, __HIP_MEMORY_SCOPE_AGENT) < (u32)NBLK)
            __builtin_amdgcn_s_sleep(8);
        __threadfence();   // single acquire fence
    }
    __syncthreads();

    int tot = (int)__hip_atomic_load(&ctr[0], __ATOMIC_RELAXED, __HIP_MEMORY_SCOPE_AGENT);
    if (tot > PAIR_CAP) tot = PAIR_CAP;

    for (int j = 0; j < 8; ++j) {
        int b = blockIdx.x * 8 + j;
        __syncthreads();                 // protect act reuse across batches
        if (tid == 0) { n1s = 0; n2s = 0; }
        __syncthreads();

        for (int i = tid; i < tot; i += 256) {
            u32 p = __hip_atomic_load(&pairs[i], __ATOMIC_RELAXED, __HIP_MEMORY_SCOPE_AGENT);
            if ((int)(p >> 13) == b) {
                int pos = atomicAdd(&n1s, 1);
                if (pos < MAXACT) act1[pos] = (int)(p & 8191u);
            }
        }
        __syncthreads();
        if (tid == 0) {
            int c = n1s; if (c > MAXACT) { c = MAXACT; n1s = c; }
            for (int i = 1; i < c; ++i) {            // deterministic ascending order
                int v = act1[i], k = i;
                while (k > 0 && act1[k - 1] > v) { act1[k] = act1[k - 1]; --k; }
                act1[k] = v;
            }
        }
        __syncthreads();
        int na1 = n1s;

        if (na1 >= THRESH) {   // exactness path; W2 entries <= +1 make z2<16 otherwise
            for (int nn = tid; nn < HIDDEN; nn += 256) {
                int z = 0;
                for (int i = 0; i < na1; ++i) z += (int)W2[(size_t)nn * HIDDEN + act1[i]];
                if (z >= THRESH) {
                    int pos = atomicAdd(&n2s, 1);
                    if (pos < MAXACT) act2[pos] = nn;
                }
            }
            __syncthreads();
            if (tid == 0) {
                int c = n2s; if (c > MAXACT) { c = MAXACT; n2s = c; }
                for (int i = 1; i < c; ++i) {
                    int v = act2[i], k = i;
                    while (k > 0 && act2[k - 1] > v) { act2[k] = act2[k - 1]; --k; }
                    act2[k] = v;
                }
            }
            __syncthreads();
        }
        int na2 = n2s;

        float s0 = 0.f, s1 = 0.f, s2 = 0.f, s3 = 0.f;
        for (int i = 0; i < na1; ++i) {
            const float* wr = Wout + (size_t)act1[i] * CLASSES;   // layer 0
            s0 += wr[tid];
            s1 += wr[tid + 256];
            s2 += wr[tid + 512];
            if (tid + 768 < CLASSES) s3 += wr[tid + 768];
        }
        for (int i = 0; i < na2; ++i) {
            const float* wr = Wout + (size_t)HIDDEN * CLASSES + (size_t)act2[i] * CLASSES;
            s0 += wr[tid];
            s1 += wr[tid + 256];
            s2 += wr[tid + 512];
            if (tid + 768 < CLASSES) s3 += wr[tid + 768];
        }

        float* orow = outp + (size_t)b * CLASSES;
        orow[tid]       = s0;
        orow[tid + 256] = s1;
        orow[tid + 512] = s2;
        if (tid + 768 < CLASSES) orow[tid + 768] = s3;

        // fused argmax (max value, min index on ties == numpy)
        float best = s0; int bi = tid;
        if (s1 > best) { best = s1; bi = tid + 256; }
        if (s2 > best) { best = s2; bi = tid + 512; }
        if (tid + 768 < CLASSES && s3 > best) { best = s3; bi = tid + 768; }
        rv[tid] = best; ri[tid] = bi;
        __syncthreads();
        for (int off = 128; off; off >>= 1) {
            if (tid < off) {
                float ov = rv[tid + off]; int oi = ri[tid + off];
                if (ov > rv[tid] || (ov == rv[tid] && oi < ri[tid])) { rv[tid] = ov; ri[tid] = oi; }
            }
            __syncthreads();
        }
        if (tid == 0) pred[b] = (float)ri[0];
    }
}

extern "C" void kernel_launch(void* const* d_in, const int* in_sizes, int n_in,
                              void* d_out, int out_size, void* d_ws, size_t ws_size,
                              hipStream_t stream) {
    (void)in_sizes; (void)n_in; (void)out_size; (void)ws_size;
    const float* x    = (const float*)d_in[0];
    const float* W1   = (const float*)d_in[1];
    const float* W2   = (const float*)d_in[2];
    const float* Wout = (const float*)d_in[3];

    float* pred = (float*)d_out;          // 512 predictions (as float)
    float* outp = (float*)d_out + BATCH;  // 512 x 1000 logits

    char* ws = (char*)d_ws;
    u32* ctr   = (u32*)(ws + OFF_CTR);
    u32* a0t_w = (u32*)(ws + OFF_A0T);
    u32* pairs = (u32*)(ws + OFF_PAIRS);

    hipMemsetAsync(ctr, 0, 16, stream);
    fused_kernel<<<NBLK, 256, 0, stream>>>(x, W1, W2, Wout, ctr, a0t_w, pairs, outp, pred);
}

// Round 6
// 91.299 us; speedup vs baseline: 7.0674x; 1.7692x over previous
//
#include <hip/hip_runtime.h>

#define BATCH 512
#define FEATURES 256
#define ENC 2048
#define HIDDEN 8192
#define CLASSES 1000
#define THRESH 16
#define PAIR_CAP 65536
#define MAXACT 256
#define NBLK 2048
#define OUTBLK 64
#define NPREP 16

typedef unsigned long long u64;
typedef unsigned int u32;

// -------- workspace layout (bytes) --------
// Sync state is SPREAD ACROSS CACHELINES (R5 post-mortem: 4K same-line
// agent RMWs serialize at ~40ns each at the coherence point = the whole
// 170us). Word indices into sync[] (u32):
//   [0]            npairs                  (own line)
//   [32..47]       prep flags, 16 words    (one line, 16 stores total)
//   [64 + 32k]     go replica k, k<64      (64 lines; 32 readers each)
//   [2112 + 32k]   subcounter k, k<64      (64 lines; 32 RMWs each)
//   [4160]         lvl2                    (own line; 64 RMWs)
// bytes [0, 16896) memset to 0 each launch.
#define W_NPAIRS 0
#define W_FLAGS  32
#define W_GO     64
#define W_SUB    2112
#define W_LVL2   4160
#define OFF_A0T   16896
#define OFF_PAIRS (16896 + 131072)
// total ws use = OFF_PAIRS + PAIR_CAP*4 = 410112 bytes

__global__ __launch_bounds__(256, 8) void fused_kernel(
    const float* __restrict__ x, const float* __restrict__ W1,
    const float* __restrict__ W2, const float* __restrict__ Wout,
    u32* sync, u32* a0t_w, u32* pairs, float* outp, float* pred)
{
    const unsigned char* a0t = (const unsigned char*)a0t_w;
    int tid = threadIdx.x;
    int wid = tid >> 6, lane = tid & 63;
    int bid = blockIdx.x;
    __shared__ int colsAll[4][40];
    __shared__ int act1[MAXACT], act2[MAXACT];
    __shared__ int n1s, n2s;
    __shared__ float rv[256];
    __shared__ int ri[256];

    // ---- prep: blocks 0..15 (static; co-residency guaranteed by
    //      __launch_bounds__(256,8) with grid == 8*256) ----
    if (bid < NPREP) {
        int w = bid, f = tid;            // 32-batch word w, feature f
        u32 m[8] = {0,0,0,0,0,0,0,0};
        for (int i = 0; i < 32; ++i) {
            float v = x[(w * 32 + i) * FEATURES + f];
            v = fminf(fmaxf(v, 0.0f), 1.0f);
            int lvl = (int)rintf(v * 255.0f);   // round-half-even == np.round
            int g = lvl ^ (lvl >> 1);
            u32 bit = 1u << i;
#pragma unroll
            for (int k = 0; k < 8; ++k) if ((g >> k) & 1) m[k] |= bit;
        }
#pragma unroll
        for (int k = 0; k < 8; ++k) a0t_w[(f * 8 + k) * 16 + w] = m[k];
        __syncthreads();
        if (tid == 0)   // release store: writes back this XCD's dirty a0t lines
            __hip_atomic_store(&sync[W_FLAGS + w], 1u,
                               __ATOMIC_RELEASE, __HIP_MEMORY_SCOPE_AGENT);
    }

    // ---- block 0 aggregates prep flags, broadcasts 64 go replicas ----
    if (bid == 0 && tid == 0) {
        for (;;) {
            u32 s = 0;
            for (int t = 0; t < NPREP; ++t)
                s += __hip_atomic_load(&sync[W_FLAGS + t],
                                       __ATOMIC_RELAXED, __HIP_MEMORY_SCOPE_AGENT);
            if (s == NPREP) break;
            __builtin_amdgcn_s_sleep(8);
        }
        __threadfence();   // order go-stores after flag-loads
        for (int k = 0; k < 64; ++k)
            __hip_atomic_store(&sync[W_GO + 32 * k], 1u,
                               __ATOMIC_RELAXED, __HIP_MEMORY_SCOPE_AGENT);
    }

    // ---- z1 phase A: stream W1 rows (float4), compact (col,sign) to LDS ----
    // (no a0t dependency — the 64 MB stream hides prep latency)
    int n = bid * 4 + wid;
    const float4* rowv = reinterpret_cast<const float4*>(W1 + (size_t)n * ENC);
    int* cols = colsAll[wid];
    int cnt = 0;
    u64 lmask = (lane == 63) ? 0x7fffffffffffffffULL : ((1ULL << lane) - 1ULL);
    for (int it = 0; it < 8; ++it) {
        float4 v = rowv[it * 64 + lane];
#pragma unroll
        for (int c = 0; c < 4; ++c) {
            float vc = (c == 0) ? v.x : (c == 1) ? v.y : (c == 2) ? v.z : v.w;
            u64 mm = __ballot(vc != 0.0f);
            if (vc != 0.0f) {
                int pos = cnt + __popcll(mm & lmask);
                cols[pos] = ((it * 256 + lane * 4 + c) << 1) | (vc < 0.0f ? 1 : 0);
            }
            cnt += __popcll(mm);
        }
    }

    // ---- wait for a0t: poll own go replica (reads only), fence once ----
    if (tid == 0) {
        while (__hip_atomic_load(&sync[W_GO + 32 * (bid & 63)],
                                 __ATOMIC_RELAXED, __HIP_MEMORY_SCOPE_AGENT) == 0u)
            __builtin_amdgcn_s_sleep(16);
        __threadfence();   // single inv: subsequent plain a0t loads are fresh
    }
    __syncthreads();

    // ---- z1 phase B: bit-sliced carry-save accumulate over entries ----
    u32 p0=0,p1=0,p2=0,p3=0,p4=0,p5=0;
    u32 q0=0,q1=0,q2=0,q3=0,q4=0,q5=0;
#pragma unroll 4
    for (int i = 0; i < cnt; ++i) {
        int e = __builtin_amdgcn_readfirstlane(cols[i]);
        u32 m = a0t[(size_t)(e >> 1) * 64 + lane];
        if (e & 1) {   // negative (wave-uniform branch)
            u32 t;
            t = q0 & m; q0 ^= m; m = t;
            t = q1 & m; q1 ^= m; m = t;
            t = q2 & m; q2 ^= m; m = t;
            t = q3 & m; q3 ^= m; m = t;
            t = q4 & m; q4 ^= m; m = t;
            q5 ^= m;
        } else {
            u32 t;
            t = p0 & m; p0 ^= m; m = t;
            t = p1 & m; p1 ^= m; m = t;
            t = p2 & m; p2 ^= m; m = t;
            t = p3 & m; p3 ^= m; m = t;
            p5 ^= (p4 & m); p4 ^= m;
        }
    }

    u32 cand = p4 | p5;     // bytes where P >= 16 possible (z>=16 requires P>=16)
    while (cand) {
        int k = __ffs(cand) - 1;
        cand &= cand - 1;
        int P = ((p0 >> k) & 1) | (((p1 >> k) & 1) << 1) | (((p2 >> k) & 1) << 2) |
                (((p3 >> k) & 1) << 3) | (((p4 >> k) & 1) << 4) | (((p5 >> k) & 1) << 5);
        int N = ((q0 >> k) & 1) | (((q1 >> k) & 1) << 1) | (((q2 >> k) & 1) << 2) |
                (((q3 >> k) & 1) << 3) | (((q4 >> k) & 1) << 4) | (((q5 >> k) & 1) << 5);
        if (P - N >= THRESH) {
            int b = lane * 8 + k;
            u32 pos = __hip_atomic_fetch_add(&sync[W_NPAIRS], 1u,
                                             __ATOMIC_RELAXED, __HIP_MEMORY_SCOPE_AGENT);
            if (pos < PAIR_CAP)
                __hip_atomic_store(&pairs[pos], ((u32)b << 13) | (u32)n,
                                   __ATOMIC_RELAXED, __HIP_MEMORY_SCOPE_AGENT);
        }
    }

    // ---- z1-done tree: increment spread subcounter (32 RMWs per line) ----
    // __syncthreads drains the agent-scope pair stores (vmcnt 0) first.
    __syncthreads();
    if (tid == 0)
        __hip_atomic_fetch_add(&sync[W_SUB + 32 * (bid & 63)], 1u,
                               __ATOMIC_RELAXED, __HIP_MEMORY_SCOPE_AGENT);
    if (bid >= OUTBLK) return;

    // ---- out phase: 64 blocks x 8 batches ----
    // block g: wait sub[g]==32, one lvl2 RMW, wait lvl2==64.
    if (tid == 0) {
        while (__hip_atomic_load(&sync[W_SUB + 32 * bid],
                                 __ATOMIC_RELAXED, __HIP_MEMORY_SCOPE_AGENT) < (u32)(NBLK / 64))
            __builtin_amdgcn_s_sleep(8);
        __hip_atomic_fetch_add(&sync[W_LVL2], 1u,
                               __ATOMIC_RELAXED, __HIP_MEMORY_SCOPE_AGENT);
        while (__hip_atomic_load(&sync[W_LVL2],
                                 __ATOMIC_RELAXED, __HIP_MEMORY_SCOPE_AGENT) < (u32)OUTBLK)
            __builtin_amdgcn_s_sleep(8);
        __threadfence();
    }
    __syncthreads();

    int tot = (int)__hip_atomic_load(&sync[W_NPAIRS],
                                     __ATOMIC_RELAXED, __HIP_MEMORY_SCOPE_AGENT);
    if (tot > PAIR_CAP) tot = PAIR_CAP;

    for (int j = 0; j < 8; ++j) {
        int b = bid * 8 + j;
        __syncthreads();                 // protect act reuse across batches
        if (tid == 0) { n1s = 0; n2s = 0; }
        __syncthreads();

        for (int i = tid; i < tot; i += 256) {
            u32 p = __hip_atomic_load(&pairs[i], __ATOMIC_RELAXED, __HIP_MEMORY_SCOPE_AGENT);
            if ((int)(p >> 13) == b) {
                int pos = atomicAdd(&n1s, 1);
                if (pos < MAXACT) act1[pos] = (int)(p & 8191u);
            }
        }
        __syncthreads();
        if (tid == 0) {
            int c = n1s; if (c > MAXACT) { c = MAXACT; n1s = c; }
            for (int i = 1; i < c; ++i) {            // deterministic ascending order
                int v = act1[i], k = i;
                while (k > 0 && act1[k - 1] > v) { act1[k] = act1[k - 1]; --k; }
                act1[k] = v;
            }
        }
        __syncthreads();
        int na1 = n1s;

        if (na1 >= THRESH) {   // exactness path; W2 entries <= +1 make z2<16 otherwise
            for (int nn = tid; nn < HIDDEN; nn += 256) {
                int z = 0;
                for (int i = 0; i < na1; ++i) z += (int)W2[(size_t)nn * HIDDEN + act1[i]];
                if (z >= THRESH) {
                    int pos = atomicAdd(&n2s, 1);
                    if (pos < MAXACT) act2[pos] = nn;
                }
            }
            __syncthreads();
            if (tid == 0) {
                int c = n2s; if (c > MAXACT) { c = MAXACT; n2s = c; }
                for (int i = 1; i < c; ++i) {
                    int v = act2[i], k = i;
                    while (k > 0 && act2[k - 1] > v) { act2[k] = act2[k - 1]; --k; }
                    act2[k] = v;
                }
            }
            __syncthreads();
        }
        int na2 = n2s;

        float s0 = 0.f, s1 = 0.f, s2 = 0.f, s3 = 0.f;
        for (int i = 0; i < na1; ++i) {
            const float* wr = Wout + (size_t)act1[i] * CLASSES;   // layer 0
            s0 += wr[tid];
            s1 += wr[tid + 256];
            s2 += wr[tid + 512];
            if (tid + 768 < CLASSES) s3 += wr[tid + 768];
        }
        for (int i = 0; i < na2; ++i) {
            const float* wr = Wout + (size_t)HIDDEN * CLASSES + (size_t)act2[i] * CLASSES;
            s0 += wr[tid];
            s1 += wr[tid + 256];
            s2 += wr[tid + 512];
            if (tid + 768 < CLASSES) s3 += wr[tid + 768];
        }

        float* orow = outp + (size_t)b * CLASSES;
        orow[tid]       = s0;
        orow[tid + 256] = s1;
        orow[tid + 512] = s2;
        if (tid + 768 < CLASSES) orow[tid + 768] = s3;

        // fused argmax (max value, min index on ties == numpy)
        float best = s0; int bi = tid;
        if (s1 > best) { best = s1; bi = tid + 256; }
        if (s2 > best) { best = s2; bi = tid + 512; }
        if (tid + 768 < CLASSES && s3 > best) { best = s3; bi = tid + 768; }
        rv[tid] = best; ri[tid] = bi;
        __syncthreads();
        for (int off = 128; off; off >>= 1) {
            if (tid < off) {
                float ov = rv[tid + off]; int oi = ri[tid + off];
                if (ov > rv[tid] || (ov == rv[tid] && oi < ri[tid])) { rv[tid] = ov; ri[tid] = oi; }
            }
            __syncthreads();
        }
        if (tid == 0) pred[b] = (float)ri[0];
    }
}

extern "C" void kernel_launch(void* const* d_in, const int* in_sizes, int n_in,
                              void* d_out, int out_size, void* d_ws, size_t ws_size,
                              hipStream_t stream) {
    (void)in_sizes; (void)n_in; (void)out_size; (void)ws_size;
    const float* x    = (const float*)d_in[0];
    const float* W1   = (const float*)d_in[1];
    const float* W2   = (const float*)d_in[2];
    const float* Wout = (const float*)d_in[3];

    float* pred = (float*)d_out;          // 512 predictions (as float)
    float* outp = (float*)d_out + BATCH;  // 512 x 1000 logits

    char* ws = (char*)d_ws;
    u32* sync  = (u32*)ws;
    u32* a0t_w = (u32*)(ws + OFF_A0T);
    u32* pairs = (u32*)(ws + OFF_PAIRS);

    hipMemsetAsync(sync, 0, OFF_A0T, stream);
    fused_kernel<<<NBLK, 256, 0, stream>>>(x, W1, W2, Wout, sync, a0t_w, pairs, outp, pred);
}

// Round 7
// 60.471 us; speedup vs baseline: 10.6703x; 1.5098x over previous
//
#include <hip/hip_runtime.h>

#define BATCH 512
#define FEATURES 256
#define ENC 2048
#define HIDDEN 8192
#define CLASSES 1000
#define THRESH 16
#define PAIR_CAP 65536
#define MAXACT 256
#define NBLK 2048
#define OUTBLK 64
#define NPREP 16

typedef unsigned long long u64;
typedef unsigned int u32;

// -------- workspace layout (bytes) --------
// Sync words (u32 indices into sync[]), spread across cachelines (R5 lesson:
// same-line agent RMWs serialize ~40ns each at the coherence point):
//   [0]            npairs               (own line; ~130 RMWs)
//   [2112 + 32k]   subcounter k, k<64   (64 lines; 32 RMWs each)
//   [4160]         lvl2                 (own line; 64 RMWs)
// Words [0, 4224) are zeroed by prep_kernel EVERY launch (no memset node:
// R6 post-mortem — a 16.5 KB hipMemsetAsync graph node ran at 155 us).
#define W_NPAIRS 0
#define W_SUB    2112
#define W_LVL2   4160
#define SYNC_WORDS 4224
#define OFF_A0T   16896
#define OFF_PAIRS (16896 + 131072)
// total ws use = OFF_PAIRS + PAIR_CAP*4 = 410112 bytes

// Dispatch 1: zero sync area + build a0t (transposed gray-code bit columns).
// Stream ordering to dispatch 2 replaces all go-flag machinery.
__global__ __launch_bounds__(256) void prep_kernel(const float* __restrict__ x,
                                                   u32* __restrict__ sync,
                                                   u32* __restrict__ a0t_w) {
    int bid = blockIdx.x;        // 0..15
    int tid = threadIdx.x;
    for (int i = bid * 256 + tid; i < SYNC_WORDS; i += NPREP * 256)
        sync[i] = 0u;

    int w = bid, f = tid;        // 32-batch word w, feature f
    u32 m[8] = {0,0,0,0,0,0,0,0};
    for (int i = 0; i < 32; ++i) {
        float v = x[(w * 32 + i) * FEATURES + f];
        v = fminf(fmaxf(v, 0.0f), 1.0f);
        int lvl = (int)rintf(v * 255.0f);   // round-half-even == np.round
        int g = lvl ^ (lvl >> 1);
        u32 bit = 1u << i;
#pragma unroll
        for (int k = 0; k < 8; ++k) if ((g >> k) & 1) m[k] |= bit;
    }
#pragma unroll
    for (int k = 0; k < 8; ++k) a0t_w[(f * 8 + k) * 16 + w] = m[k];
}

// Dispatch 2: z1 (W1 stream + bit-sliced threshold) fused with the out phase
// via the spread sub-counter tree (proven in R6, absmax 0).
__global__ __launch_bounds__(256, 8) void fused_kernel(
    const float* __restrict__ W1, const float* __restrict__ W2,
    const float* __restrict__ Wout,
    u32* sync, const u32* __restrict__ a0t_w, u32* pairs,
    float* outp, float* pred)
{
    const unsigned char* a0t = (const unsigned char*)a0t_w;
    int tid = threadIdx.x;
    int wid = tid >> 6, lane = tid & 63;
    int bid = blockIdx.x;
    __shared__ int colsAll[4][40];
    __shared__ int act1[MAXACT], act2[MAXACT];
    __shared__ int n1s, n2s;
    __shared__ float rv[256];
    __shared__ int ri[256];

    // ---- z1 phase A: stream W1 rows (float4), compact (col,sign) to LDS ----
    int n = bid * 4 + wid;
    const float4* rowv = reinterpret_cast<const float4*>(W1 + (size_t)n * ENC);
    int* cols = colsAll[wid];
    int cnt = 0;
    u64 lmask = (lane == 63) ? 0x7fffffffffffffffULL : ((1ULL << lane) - 1ULL);
    for (int it = 0; it < 8; ++it) {
        float4 v = rowv[it * 64 + lane];
#pragma unroll
        for (int c = 0; c < 4; ++c) {
            float vc = (c == 0) ? v.x : (c == 1) ? v.y : (c == 2) ? v.z : v.w;
            u64 mm = __ballot(vc != 0.0f);
            if (vc != 0.0f) {
                int pos = cnt + __popcll(mm & lmask);
                cols[pos] = ((it * 256 + lane * 4 + c) << 1) | (vc < 0.0f ? 1 : 0);
            }
            cnt += __popcll(mm);
        }
    }
    __syncthreads();   // cols[] visible to the whole wave (LDS)

    // ---- z1 phase B: bit-sliced carry-save accumulate over entries ----
    u32 p0=0,p1=0,p2=0,p3=0,p4=0,p5=0;
    u32 q0=0,q1=0,q2=0,q3=0,q4=0,q5=0;
#pragma unroll 4
    for (int i = 0; i < cnt; ++i) {
        int e = __builtin_amdgcn_readfirstlane(cols[i]);
        u32 m = a0t[(size_t)(e >> 1) * 64 + lane];
        if (e & 1) {   // negative (wave-uniform branch)
            u32 t;
            t = q0 & m; q0 ^= m; m = t;
            t = q1 & m; q1 ^= m; m = t;
            t = q2 & m; q2 ^= m; m = t;
            t = q3 & m; q3 ^= m; m = t;
            t = q4 & m; q4 ^= m; m = t;
            q5 ^= m;
        } else {
            u32 t;
            t = p0 & m; p0 ^= m; m = t;
            t = p1 & m; p1 ^= m; m = t;
            t = p2 & m; p2 ^= m; m = t;
            t = p3 & m; p3 ^= m; m = t;
            p5 ^= (p4 & m); p4 ^= m;
        }
    }

    u32 cand = p4 | p5;     // bytes where P >= 16 possible (z>=16 requires P>=16)
    while (cand) {
        int k = __ffs(cand) - 1;
        cand &= cand - 1;
        int P = ((p0 >> k) & 1) | (((p1 >> k) & 1) << 1) | (((p2 >> k) & 1) << 2) |
                (((p3 >> k) & 1) << 3) | (((p4 >> k) & 1) << 4) | (((p5 >> k) & 1) << 5);
        int N = ((q0 >> k) & 1) | (((q1 >> k) & 1) << 1) | (((q2 >> k) & 1) << 2) |
                (((q3 >> k) & 1) << 3) | (((q4 >> k) & 1) << 4) | (((q5 >> k) & 1) << 5);
        if (P - N >= THRESH) {
            int b = lane * 8 + k;
            u32 pos = __hip_atomic_fetch_add(&sync[W_NPAIRS], 1u,
                                             __ATOMIC_RELAXED, __HIP_MEMORY_SCOPE_AGENT);
            if (pos < PAIR_CAP)
                __hip_atomic_store(&pairs[pos], ((u32)b << 13) | (u32)n,
                                   __ATOMIC_RELAXED, __HIP_MEMORY_SCOPE_AGENT);
        }
    }

    // ---- z1-done tree: spread subcounters (32 RMWs per line) ----
    // __syncthreads drains this block's agent-scope pair stores first.
    __syncthreads();
    if (tid == 0)
        __hip_atomic_fetch_add(&sync[W_SUB + 32 * (bid & 63)], 1u,
                               __ATOMIC_RELAXED, __HIP_MEMORY_SCOPE_AGENT);
    if (bid >= OUTBLK) return;

    // ---- out phase: 64 blocks x 8 batches ----
    if (tid == 0) {
        while (__hip_atomic_load(&sync[W_SUB + 32 * bid],
                                 __ATOMIC_RELAXED, __HIP_MEMORY_SCOPE_AGENT) < (u32)(NBLK / 64))
            __builtin_amdgcn_s_sleep(8);
        __hip_atomic_fetch_add(&sync[W_LVL2], 1u,
                               __ATOMIC_RELAXED, __HIP_MEMORY_SCOPE_AGENT);
        while (__hip_atomic_load(&sync[W_LVL2],
                                 __ATOMIC_RELAXED, __HIP_MEMORY_SCOPE_AGENT) < (u32)OUTBLK)
            __builtin_amdgcn_s_sleep(8);
        __threadfence();   // single acquire fence (64 blocks total)
    }
    __syncthreads();

    int tot = (int)__hip_atomic_load(&sync[W_NPAIRS],
                                     __ATOMIC_RELAXED, __HIP_MEMORY_SCOPE_AGENT);
    if (tot > PAIR_CAP) tot = PAIR_CAP;

    for (int j = 0; j < 8; ++j) {
        int b = bid * 8 + j;
        __syncthreads();                 // protect act reuse across batches
        if (tid == 0) { n1s = 0; n2s = 0; }
        __syncthreads();

        for (int i = tid; i < tot; i += 256) {
            u32 p = __hip_atomic_load(&pairs[i], __ATOMIC_RELAXED, __HIP_MEMORY_SCOPE_AGENT);
            if ((int)(p >> 13) == b) {
                int pos = atomicAdd(&n1s, 1);
                if (pos < MAXACT) act1[pos] = (int)(p & 8191u);
            }
        }
        __syncthreads();
        if (tid == 0) {
            int c = n1s; if (c > MAXACT) { c = MAXACT; n1s = c; }
            for (int i = 1; i < c; ++i) {            // deterministic ascending order
                int v = act1[i], k = i;
                while (k > 0 && act1[k - 1] > v) { act1[k] = act1[k - 1]; --k; }
                act1[k] = v;
            }
        }
        __syncthreads();
        int na1 = n1s;

        if (na1 >= THRESH) {   // exactness path; W2 entries <= +1 make z2<16 otherwise
            for (int nn = tid; nn < HIDDEN; nn += 256) {
                int z = 0;
                for (int i = 0; i < na1; ++i) z += (int)W2[(size_t)nn * HIDDEN + act1[i]];
                if (z >= THRESH) {
                    int pos = atomicAdd(&n2s, 1);
                    if (pos < MAXACT) act2[pos] = nn;
                }
            }
            __syncthreads();
            if (tid == 0) {
                int c = n2s; if (c > MAXACT) { c = MAXACT; n2s = c; }
                for (int i = 1; i < c; ++i) {
                    int v = act2[i], k = i;
                    while (k > 0 && act2[k - 1] > v) { act2[k] = act2[k - 1]; --k; }
                    act2[k] = v;
                }
            }
            __syncthreads();
        }
        int na2 = n2s;

        float s0 = 0.f, s1 = 0.f, s2 = 0.f, s3 = 0.f;
        for (int i = 0; i < na1; ++i) {
            const float* wr = Wout + (size_t)act1[i] * CLASSES;   // layer 0
            s0 += wr[tid];
            s1 += wr[tid + 256];
            s2 += wr[tid + 512];
            if (tid + 768 < CLASSES) s3 += wr[tid + 768];
        }
        for (int i = 0; i < na2; ++i) {
            const float* wr = Wout + (size_t)HIDDEN * CLASSES + (size_t)act2[i] * CLASSES;
            s0 += wr[tid];
            s1 += wr[tid + 256];
            s2 += wr[tid + 512];
            if (tid + 768 < CLASSES) s3 += wr[tid + 768];
        }

        float* orow = outp + (size_t)b * CLASSES;
        orow[tid]       = s0;
        orow[tid + 256] = s1;
        orow[tid + 512] = s2;
        if (tid + 768 < CLASSES) orow[tid + 768] = s3;

        // fused argmax (max value, min index on ties == numpy)
        float best = s0; int bi = tid;
        if (s1 > best) { best = s1; bi = tid + 256; }
        if (s2 > best) { best = s2; bi = tid + 512; }
        if (tid + 768 < CLASSES && s3 > best) { best = s3; bi = tid + 768; }
        rv[tid] = best; ri[tid] = bi;
        __syncthreads();
        for (int off = 128; off; off >>= 1) {
            if (tid < off) {
                float ov = rv[tid + off]; int oi = ri[tid + off];
                if (ov > rv[tid] || (ov == rv[tid] && oi < ri[tid])) { rv[tid] = ov; ri[tid] = oi; }
            }
            __syncthreads();
        }
        if (tid == 0) pred[b] = (float)ri[0];
    }
}

extern "C" void kernel_launch(void* const* d_in, const int* in_sizes, int n_in,
                              void* d_out, int out_size, void* d_ws, size_t ws_size,
                              hipStream_t stream) {
    (void)in_sizes; (void)n_in; (void)out_size; (void)ws_size;
    const float* x    = (const float*)d_in[0];
    const float* W1   = (const float*)d_in[1];
    const float* W2   = (const float*)d_in[2];
    const float* Wout = (const float*)d_in[3];

    float* pred = (float*)d_out;          // 512 predictions (as float)
    float* outp = (float*)d_out + BATCH;  // 512 x 1000 logits

    char* ws = (char*)d_ws;
    u32* sync  = (u32*)ws;
    u32* a0t_w = (u32*)(ws + OFF_A0T);
    u32* pairs = (u32*)(ws + OFF_PAIRS);

    prep_kernel<<<NPREP, 256, 0, stream>>>(x, sync, a0t_w);
    fused_kernel<<<NBLK, 256, 0, stream>>>(W1, W2, Wout, sync, a0t_w, pairs, outp, pred);
}